// Round 11
// baseline (1980.556 us; speedup 1.0000x reference)
//
#include <hip/hip_runtime.h>
#include <math.h>

#define N 8192
#define NITER 10

// ws layout (floats): slots[256] | vbuf[N] | ubuf[N] | partials[128*N]
// slot chain: slot[0]=sumsq(u0); iter k: rowdot reads slot[2k] writes slot[2k+1];
//             colacc_reduce reads slot[2k+1] writes slot[2k+2]. sigma = sqrt(slot[20]).
// All vectors are stored UNNORMALIZED; consumers multiply by rsqrt(slot).
// sigma = v_n W u_n^T = ||v_n W|| = sqrt(slot[20]).

__global__ __launch_bounds__(1024) void init_kernel(const float* __restrict__ u0,
                                                    float* __restrict__ slots) {
    // 1 block x 1024 threads: sumsq of u0 into slots[0], zero slots[1..63]
    __shared__ float red[16];
    int t = threadIdx.x;
    float acc = 0.f;
    const float4* u4 = (const float4*)u0;
    for (int i = t; i < N / 4; i += 1024) {
        float4 a = u4[i];
        acc += a.x * a.x + a.y * a.y + a.z * a.z + a.w * a.w;
    }
    for (int off = 32; off; off >>= 1) acc += __shfl_down(acc, off, 64);
    if ((t & 63) == 0) red[t >> 6] = acc;
    __syncthreads();
    if (t < 64) {
        float r = (t < 16) ? red[t] : 0.f;
        for (int off = 8; off; off >>= 1) r += __shfl_down(r, off, 64);
        if (t == 0) slots[0] = r;
    }
    if (t >= 1 && t < 64) slots[t] = 0.f;
}

// v[row] = rsqrt(*scaleSlot) * sum_j x[j]*W[row][j]; atomicAdd v^2 into sumsqSlot.
// grid 2048 x 256 threads; one wave (64 lanes) per row.
__global__ __launch_bounds__(256) void rowdot(const float* __restrict__ W,
                                              const float* __restrict__ x,
                                              float* __restrict__ y,
                                              const float* __restrict__ scaleSlot,
                                              float* __restrict__ sumsqSlot) {
    int wave = threadIdx.x >> 6;  // 0..3
    int lane = threadIdx.x & 63;
    int row = blockIdx.x * 4 + wave;
    const float4* Wr = (const float4*)(W + (size_t)row * N);
    const float4* xv = (const float4*)x;
    float4 acc4 = make_float4(0.f, 0.f, 0.f, 0.f);
#pragma unroll 8
    for (int w = 0; w < 32; ++w) {
        float4 a = Wr[lane + w * 64];
        float4 b = xv[lane + w * 64];
        acc4.x = fmaf(a.x, b.x, acc4.x);
        acc4.y = fmaf(a.y, b.y, acc4.y);
        acc4.z = fmaf(a.z, b.z, acc4.z);
        acc4.w = fmaf(a.w, b.w, acc4.w);
    }
    float acc = (acc4.x + acc4.y) + (acc4.z + acc4.w);
    for (int off = 32; off; off >>= 1) acc += __shfl_down(acc, off, 64);
    if (lane == 0) {
        float s = rsqrtf(*scaleSlot);
        float v = acc * s;
        y[row] = v;
        atomicAdd(sumsqSlot, v * v);
    }
}

// partials[rowchunk][col] = sum over 64 rows of x[row]*W[row][col] (no scale yet).
// grid 1024 (= 128 rowchunks x 8 colblocks) x 256 threads, float4 per thread.
__global__ __launch_bounds__(256) void colacc_partial(const float* __restrict__ W,
                                                      const float* __restrict__ x,
                                                      float* __restrict__ partials) {
    int colblock = blockIdx.x & 7;
    int rowchunk = blockIdx.x >> 3;
    int c4 = colblock * 256 + threadIdx.x;  // float4 column index, 0..2047
    int row0 = rowchunk * 64;
    const float4* W4 = (const float4*)W;
    float4 acc = make_float4(0.f, 0.f, 0.f, 0.f);
#pragma unroll 4
    for (int r = 0; r < 64; ++r) {
        float xv = x[row0 + r];
        float4 w = W4[(size_t)(row0 + r) * (N / 4) + c4];
        acc.x = fmaf(xv, w.x, acc.x);
        acc.y = fmaf(xv, w.y, acc.y);
        acc.z = fmaf(xv, w.z, acc.z);
        acc.w = fmaf(xv, w.w, acc.w);
    }
    ((float4*)partials)[(size_t)rowchunk * (N / 4) + c4] = acc;
}

// y[j] = rsqrt(*scaleSlot) * sum_p partials[p][j]; atomicAdd block-sum of y^2.
// grid 64 x 128 threads (one column per thread).
__global__ __launch_bounds__(128) void colacc_reduce(const float* __restrict__ partials,
                                                     float* __restrict__ y,
                                                     const float* __restrict__ scaleSlot,
                                                     float* __restrict__ sumsqSlot) {
    int j = blockIdx.x * 128 + threadIdx.x;
    float acc = 0.f;
#pragma unroll 16
    for (int p = 0; p < 128; ++p) acc += partials[(size_t)p * N + j];
    float s = rsqrtf(*scaleSlot);
    float v = acc * s;
    y[j] = v;
    float ss = v * v;
    for (int off = 32; off; off >>= 1) ss += __shfl_down(ss, off, 64);
    __shared__ float red[2];
    if ((threadIdx.x & 63) == 0) red[threadIdx.x >> 6] = ss;
    __syncthreads();
    if (threadIdx.x == 0) atomicAdd(sumsqSlot, red[0] + red[1]);
}

__global__ void final_kernel(const float* __restrict__ slots, float* __restrict__ out) {
    out[0] = sqrtf(slots[2 * NITER]);
}

extern "C" void kernel_launch(void* const* d_in, const int* in_sizes, int n_in,
                              void* d_out, int out_size, void* d_ws, size_t ws_size,
                              hipStream_t stream) {
    const float* W  = (const float*)d_in[0];
    const float* u0 = (const float*)d_in[1];
    float* out = (float*)d_out;

    float* slots    = (float*)d_ws;     // 256 floats
    float* vbuf     = slots + 256;      // N floats
    float* ubuf     = vbuf + N;         // N floats
    float* partials = ubuf + N;         // 128*N floats (4 MB)

    init_kernel<<<1, 1024, 0, stream>>>(u0, slots);
    for (int k = 0; k < NITER; ++k) {
        const float* x = (k == 0) ? u0 : ubuf;
        rowdot<<<2048, 256, 0, stream>>>(W, x, vbuf, slots + 2 * k, slots + 2 * k + 1);
        colacc_partial<<<1024, 256, 0, stream>>>(W, vbuf, partials);
        colacc_reduce<<<64, 128, 0, stream>>>(partials, ubuf, slots + 2 * k + 1,
                                              slots + 2 * k + 2);
    }
    final_kernel<<<1, 1, 0, stream>>>(slots, out);
}